// Round 8
// baseline (418.664 us; speedup 1.0000x reference)
//
#include <hip/hip_runtime.h>
#include <hip/hip_bf16.h>
#include <math.h>

// Problem constants
#define B_    256
#define C_    9
#define T_    128
#define D_    24
#define S_    16
#define NL_   4
#define DI_   48
#define NP_   29
#define NSEQ  (B_ * C_)   // 2304
#define NCLS_ 6

#define LOG2E 1.44269504088896f

#if __has_builtin(__builtin_amdgcn_exp2f)
#define EXP2F __builtin_amdgcn_exp2f
#else
#define EXP2F exp2f
#endif

__device__ __forceinline__ float fsilu(float x) {
    return __fdividef(x, 1.f + __expf(-x));
}

struct Params {
    const float *x;
    const float *stem_w, *stem_bn_g, *stem_bn_b, *stem_bn_m, *stem_bn_v;
    const float *pd_w, *pp_w, *patch_bn_g, *patch_bn_b, *patch_bn_m, *patch_bn_v;
    const float *pos_embed, *ln1_g, *ln1_b, *ln2_g, *ln2_b;
    const float *in_w, *conv_w, *conv_b, *xproj_w, *dt_w, *dt_b, *A_log, *Dp, *out_w;
    const float *attn_w, *attn_b, *ctx;
    float *cout;   // [NSEQ][24] workspace
};

// LayerNorm over 24 elems for 29 rows (stride 24), 8 threads per row.
__device__ __forceinline__ void ln_rows(const float* src, float* dst,
                                        const float* g, const float* bb, int tid) {
    int row = tid >> 3, sub = tid & 7;
    if (row < NP_) {
        const float* r = src + row * 24;
        float s = 0.f;
        for (int j = sub; j < 24; j += 8) s += r[j];
        s += __shfl_xor(s, 1); s += __shfl_xor(s, 2); s += __shfl_xor(s, 4);
        float mu = s * (1.f / 24.f);
        float v = 0.f;
        for (int j = sub; j < 24; j += 8) { float d0 = r[j] - mu; v = fmaf(d0, d0, v); }
        v += __shfl_xor(v, 1); v += __shfl_xor(v, 2); v += __shfl_xor(v, 4);
        float rs = rsqrtf(v * (1.f / 24.f) + 1e-5f);
        for (int j = sub; j < 24; j += 8) dst[row * 24 + j] = (r[j] - mu) * rs * g[j] + bb[j];
    }
}

// LDS layout (floats). 7192 floats = 28768 B -> 5 blocks/CU by LDS.
// NOTE launch bounds: (256,4) NOT (256,5). The min-waves arg caps the
// compiler's VGPR budget; (256,5) squeezed VGPR to 48 < scan live set ->
// scratch spills (r6: 138 MB HBM traffic). (256,4) compiles this body at
// 64 VGPR (r5 evidence) -> register file allows 8 waves/EU, so the LDS
// limit (5 blocks/CU = 20 waves) still sets occupancy. Occupancy may
// exceed the declared min when registers allow.
// Live-range overlays (all producer/consumer pairs barrier-separated):
//   hn [696..1392)  dead after P2  -> hosts bcf
//   u  [1392..2784) dead after P3  -> hosts rest of bcf, bcb, dtrf/b
//   z  [2784..4176) dead after scan-> hosts P6 output (29x24)
//   stage-A overlay xp[132]+h0p[3264] at z..ucb region [2784..6180)
#define OF_H    0       // 29x24 residual/h
#define OF_HN   696     // 29x24 LN1 out; dead after P2
#define OF_U    1392    // 29x48 xz-u; dead after P3
#define OF_BCF  696     // 29x32 (B[16]|C[16]) fwd — overlays hn+u head
#define OF_BCB  1624    // 29x32 bwd
#define OF_DTRF 2552    // 29x2
#define OF_DTRB 2610    // 29x2  (ends 2668 < 2784)
#define OF_Z    2784    // 29x48 silu(z); dead after scan
#define OF_OUT  2784    // 29x24 P6 output (overlays z)
#define OF_UCF  4176    // 29x52 uc fwd (pad 52 kills P6 stride-48 conflicts)
#define OF_UCB  5684    // 29x52 uc bwd
#define SM_TOT  7192

__global__ __launch_bounds__(256, 4) void mamba_seq_kernel(Params P) {
    __shared__ float sm[SM_TOT];
    const int tid = threadIdx.x;
    const int n = blockIdx.x;
    const int b = n / C_, cch = n - b * C_;

    float* s_h    = sm + OF_H;
    float* s_hn   = sm + OF_HN;
    float* s_u    = sm + OF_U;
    float* s_z    = sm + OF_Z;
    float* s_out  = sm + OF_OUT;
    float* s_ucf  = sm + OF_UCF;
    float* s_ucb  = sm + OF_UCB;
    float* s_bcf  = sm + OF_BCF;
    float* s_bcb  = sm + OF_BCB;
    float* s_dtrf = sm + OF_DTRF;
    float* s_dtrb = sm + OF_DTRB;

    float* xp  = sm + OF_Z;         // [132] stage-A overlay (z..ucb region)
    float* h0p = sm + OF_Z + 132;   // [24][136]

    // ---------------- Stage A: load + stem conv(k=5,p=2) + BN + SiLU ----------------
    if (tid < 132) {
        float v = 0.f;
        int t = tid - 2;
        if (t >= 0 && t < T_) v = P.x[(b * T_ + t) * C_ + cch];
        xp[tid] = v;
    }
    for (int idx = tid; idx < 24 * 8; idx += 256) {   // zero h0p pads
        int d = idx >> 3, j = idx & 7;
        h0p[d * 136 + (j < 4 ? j : j + 128)] = 0.f;
    }
    __syncthreads();
    for (int idx = tid; idx < 24 * 128; idx += 256) {
        int d = idx >> 7, t = idx & 127;
        const float* w = P.stem_w + d * 5;
        float acc = 0.f;
        #pragma unroll
        for (int k = 0; k < 5; k++) acc = fmaf(w[k], xp[t + k], acc);
        float sc = rsqrtf(P.stem_bn_v[d] + 1e-5f) * P.stem_bn_g[d];
        float val = (acc - P.stem_bn_m[d]) * sc + P.stem_bn_b[d];
        h0p[d * 136 + 4 + t] = fsilu(val);
    }
    __syncthreads();
    // ---------------- Stage B: patch depthwise (k=16,s=4,p=4) -> pd in s_u ----------
    // s_u [1392..2136) disjoint from h0p overlay [2916..6180)
    for (int idx = tid; idx < 24 * 31; idx += 256) {
        int d = idx / 31, l = idx - d * 31;
        const float* w = P.pd_w + d * 16;
        const float* src = h0p + d * 136 + l * 4;
        float acc = 0.f;
        #pragma unroll
        for (int k = 0; k < 16; k++) acc = fmaf(w[k], src[k], acc);
        s_u[idx] = acc;   // pd[d*31 + l]
    }
    __syncthreads();
    // pointwise DxD + BN + pos_embed -> s_h [29][24]
    for (int idx = tid; idx < NP_ * 24; idx += 256) {
        int l = idx / 24, e = idx - l * 24;
        const float* w = P.pp_w + e * 24;
        float acc = 0.f;
        #pragma unroll
        for (int d = 0; d < 24; d++) acc = fmaf(w[d], s_u[d * 31 + l], acc);
        float sc = rsqrtf(P.patch_bn_v[e] + 1e-5f) * P.patch_bn_g[e];
        acc = (acc - P.patch_bn_m[e]) * sc + P.patch_bn_b[e];
        s_h[idx] = acc + P.pos_embed[idx];
    }
    __syncthreads();

    // ---------------- Stage C: NL bidirectional mamba layers ----------------
    for (int il = 0; il < NL_; ++il) {
        const float* in_w_i   = P.in_w   + il * 96 * 24;
        const float* conv_w_i = P.conv_w + il * 48 * 4;
        const float* conv_b_i = P.conv_b + il * 48;
        const float* xpr_i    = P.xproj_w+ il * 34 * 48;
        const float* dt_w_i   = P.dt_w   + il * 48 * 2;
        const float* dt_b_i   = P.dt_b   + il * 48;
        const float* A_log_i  = P.A_log  + il * 48 * 16;
        const float* Dp_i     = P.Dp     + il * 48;
        const float* out_w_i  = P.out_w  + il * 24 * 48;

        // 1. LN1: s_h -> s_hn
        ln_rows(s_h, s_hn, P.ln1_g + il * 24, P.ln1_b + il * 24, tid);
        __syncthreads();

        // 2. xz = hn @ in_w^T. thread owns output channel j (weights in regs),
        //    iterates rows; activation row reads are LDS broadcasts.
        if (tid < 192) {
            int j  = tid >> 1;
            int l0 = (tid & 1) ? 15 : 0;
            int l1 = (tid & 1) ? NP_ : 15;
            const float4* w4 = (const float4*)(in_w_i + j * 24);
            float4 w0 = w4[0], w1 = w4[1], w2 = w4[2], w3 = w4[3], w4v = w4[4], w5 = w4[5];
            float* dst = (j < 48) ? (s_u + j) : (s_z + (j - 48));
            for (int l = l0; l < l1; ++l) {
                const float4* h4 = (const float4*)(s_hn + l * 24);
                float4 a0 = h4[0], a1 = h4[1], a2 = h4[2], a3 = h4[3], a4 = h4[4], a5 = h4[5];
                float acc;
                acc = a0.x * w0.x; acc = fmaf(a0.y, w0.y, acc); acc = fmaf(a0.z, w0.z, acc); acc = fmaf(a0.w, w0.w, acc);
                acc = fmaf(a1.x, w1.x, acc); acc = fmaf(a1.y, w1.y, acc); acc = fmaf(a1.z, w1.z, acc); acc = fmaf(a1.w, w1.w, acc);
                acc = fmaf(a2.x, w2.x, acc); acc = fmaf(a2.y, w2.y, acc); acc = fmaf(a2.z, w2.z, acc); acc = fmaf(a2.w, w2.w, acc);
                acc = fmaf(a3.x, w3.x, acc); acc = fmaf(a3.y, w3.y, acc); acc = fmaf(a3.z, w3.z, acc); acc = fmaf(a3.w, w3.w, acc);
                acc = fmaf(a4.x, w4v.x, acc); acc = fmaf(a4.y, w4v.y, acc); acc = fmaf(a4.z, w4v.z, acc); acc = fmaf(a4.w, w4v.w, acc);
                acc = fmaf(a5.x, w5.x, acc); acc = fmaf(a5.y, w5.y, acc); acc = fmaf(a5.z, w5.z, acc); acc = fmaf(a5.w, w5.w, acc);
                dst[l * 48] = acc;
            }
        }
        __syncthreads();

        // 3. causal (fwd) + anti-causal (bwd) depthwise conv k=4 + SiLU; silu(z) in place
        for (int idx = tid; idx < NP_ * 48; idx += 256) {
            int l = idx / 48, d = idx - l * 48;
            const float* w = conv_w_i + d * 4;
            float w0 = w[0], w1 = w[1], w2 = w[2], w3 = w[3];
            float bb = conv_b_i[d];
            float accf = bb, accb = bb;
            if (l >= 3) accf = fmaf(w0, s_u[(l - 3) * 48 + d], accf);
            if (l >= 2) accf = fmaf(w1, s_u[(l - 2) * 48 + d], accf);
            if (l >= 1) accf = fmaf(w2, s_u[(l - 1) * 48 + d], accf);
            accf = fmaf(w3, s_u[l * 48 + d], accf);
            if (l + 3 < NP_) accb = fmaf(w0, s_u[(l + 3) * 48 + d], accb);
            if (l + 2 < NP_) accb = fmaf(w1, s_u[(l + 2) * 48 + d], accb);
            if (l + 1 < NP_) accb = fmaf(w2, s_u[(l + 1) * 48 + d], accb);
            accb = fmaf(w3, s_u[l * 48 + d], accb);
            s_ucf[l * 52 + d] = fsilu(accf);
            s_ucb[l * 52 + d] = fsilu(accb);
            s_z[idx] = fsilu(s_z[idx]);
        }
        __syncthreads();

        // 4. dbl = uc @ xproj^T (both dirs). thread owns (dir, j) channel, weights in regs.
        //    Writes bc/dtr into the hn+u overlay (both dead here).
        if (tid < 204) {
            int lg = tid / 68;            // 0..2 row-group
            int ch = tid - lg * 68;       // 0..67
            int l0 = lg * 10;
            int l1 = (lg == 2) ? NP_ : (l0 + 10);
            int dir = ch >= 34;
            int j = ch - (dir ? 34 : 0);
            const float* ucp = dir ? s_ucb : s_ucf;
            const float4* w4 = (const float4*)(xpr_i + j * 48);
            float4 w[12];
            #pragma unroll
            for (int q = 0; q < 12; q++) w[q] = w4[q];
            float* dst; int stride;
            if (j < 2) { dst = (dir ? s_dtrb : s_dtrf) + j; stride = 2; }
            else       { dst = (dir ? s_bcb  : s_bcf ) + (j - 2); stride = 32; }
            for (int l = l0; l < l1; ++l) {
                const float4* u4 = (const float4*)(ucp + l * 52);
                float acc = 0.f;
                #pragma unroll
                for (int q = 0; q < 12; q++) {
                    float4 a = u4[q];
                    acc = fmaf(a.x, w[q].x, fmaf(a.y, w[q].y, fmaf(a.z, w[q].z, fmaf(a.w, w[q].w, acc))));
                }
                dst[l * stride] = acc;
            }
        }
        __syncthreads();

        // 5. selective scans, lane-pair split: 192 lanes = 2 dirs x 48 ch x 2 state-halves.
        //    Lane (dir, d, sh) owns states sh*8..sh*8+7 (hs[8] regs, B/C halved).
        //    y combined across the pair with one shfl_xor (off the recurrence chain).
        //    Pipelined: next step's dt/exp2/u/z/BC prefetched during current FMAs.
        //    Output written in place to s_ucf/s_ucb by sh==0 lane.
        if (tid < 192) {
            const int dir = tid >= 96;
            const int rr  = tid - (dir ? 96 : 0);
            const int d   = rr >> 1;
            const int sh  = rr & 1;
            const float* dtr = dir ? s_dtrb : s_dtrf;
            float* ucio      = dir ? s_ucb  : s_ucf;   // read u; write y in place
            const float* bc  = dir ? s_bcb  : s_bcf;
            const float dtw0 = dt_w_i[d * 2], dtw1 = dt_w_i[d * 2 + 1], dtb = dt_b_i[d];
            const float Dpd = Dp_i[d];
            // structure check (rolling, no array): A[s] == (s+1)*A[0]?
            float a0 = -__expf(A_log_i[d * 16]) * LOG2E;
            bool alin = true;
            #pragma unroll
            for (int s = 1; s < 16; s++) {
                float as = -__expf(A_log_i[d * 16 + s]) * LOG2E;
                alin = alin && (fabsf(as - (s + 1) * a0) <= 1e-4f * (s + 1) * fabsf(a0));
            }
            float hs[8];
            #pragma unroll
            for (int s = 0; s < 8; s++) hs[s] = 0.f;

            if (alin) {
                // ---- prologue: prefetch step 0 ----
                int l = dir ? (NP_ - 1) : 0;
                float2 tt = *(const float2*)(dtr + l * 2);
                float u_ld = ucio[l * 52 + d];
                float z_ld = s_z[l * 48 + d];
                const float4* bv = (const float4*)(bc + l * 32);
                float4 Bv0 = bv[2 * sh], Bv1 = bv[2 * sh + 1];
                float4 Cv0 = bv[4 + 2 * sh], Cv1 = bv[5 + 2 * sh];
                float draw = fmaf(tt.y, dtw1, fmaf(tt.x, dtw0, dtb));
                float dtc = (draw > 15.f) ? draw : __logf(1.f + __expf(draw));
                float dtu = dtc * u_ld;
                float r1 = EXP2F(dtc * a0);

                for (int p = 0; p < NP_; p++) {
                    // snapshot current step
                    const int lcur = l;
                    const float u_c = u_ld, z_c = z_ld, dtu_c = dtu;
                    const float4 Ba = Bv0, Bb = Bv1, Ca = Cv0, Cb = Cv1;
                    // dA powers from current r1: lane handles r^(8sh+1)..r^(8sh+8)
                    float c2 = r1 * r1, c4 = c2 * c2, c8 = c4 * c4;
                    float p3 = c2 * r1, p5 = c4 * r1, p6 = c4 * c2, p7 = c4 * p3;
                    float qm = sh ? c8 : 1.0f;
                    float dA0 = r1 * qm, dA1 = c2 * qm, dA2 = p3 * qm, dA3 = c4 * qm;
                    float dA4 = p5 * qm, dA5 = p6 * qm, dA6 = p7 * qm, dA7 = c8 * qm;
                    // ---- prefetch step p+1 (independent of recurrence) ----
                    if (p + 1 < NP_) {
                        l = dir ? (NP_ - 2 - p) : (p + 1);
                        tt = *(const float2*)(dtr + l * 2);
                        u_ld = ucio[l * 52 + d];
                        z_ld = s_z[l * 48 + d];
                        const float4* bn = (const float4*)(bc + l * 32);
                        Bv0 = bn[2 * sh]; Bv1 = bn[2 * sh + 1];
                        Cv0 = bn[4 + 2 * sh]; Cv1 = bn[5 + 2 * sh];
                        draw = fmaf(tt.y, dtw1, fmaf(tt.x, dtw0, dtb));
                        dtc = (draw > 15.f) ? draw : __logf(1.f + __expf(draw));
                        dtu = dtc * u_ld;
                        r1 = EXP2F(dtc * a0);
                    }
                    // ---- current step FMAs (8 states) ----
                    float y0, y1;
                    hs[0] = fmaf(dA0, hs[0], dtu_c * Ba.x); y0 = hs[0] * Ca.x;
                    hs[1] = fmaf(dA1, hs[1], dtu_c * Ba.y); y1 = hs[1] * Ca.y;
                    hs[2] = fmaf(dA2, hs[2], dtu_c * Ba.z); y0 = fmaf(hs[2], Ca.z, y0);
                    hs[3] = fmaf(dA3, hs[3], dtu_c * Ba.w); y1 = fmaf(hs[3], Ca.w, y1);
                    hs[4] = fmaf(dA4, hs[4], dtu_c * Bb.x); y0 = fmaf(hs[4], Cb.x, y0);
                    hs[5] = fmaf(dA5, hs[5], dtu_c * Bb.y); y1 = fmaf(hs[5], Cb.y, y1);
                    hs[6] = fmaf(dA6, hs[6], dtu_c * Bb.z); y0 = fmaf(hs[6], Cb.z, y0);
                    hs[7] = fmaf(dA7, hs[7], dtu_c * Bb.w); y1 = fmaf(hs[7], Cb.w, y1);
                    float y = y0 + y1;
                    y += __shfl_xor(y, 1);   // combine the two state-halves
                    float v = fmaf(u_c, Dpd, y) * z_c;
                    if (sh == 0) ucio[lcur * 52 + d] = v;
                }
            } else {
                // generic fallback (A without arange structure); register-light,
                // reads A_log through cache per step. Never taken for this model.
                for (int p = 0; p < NP_; p++) {
                    int l = dir ? (NP_ - 1 - p) : p;
                    float2 tt = *(const float2*)(dtr + l * 2);
                    float draw = fmaf(tt.y, dtw1, fmaf(tt.x, dtw0, dtb));
                    float dtc = (draw > 15.f) ? draw : __logf(1.f + __expf(draw));
                    float u_ld = ucio[l * 52 + d];
                    float z_ld = s_z[l * 48 + d];
                    float dtu = dtc * u_ld;
                    const float4* bv = (const float4*)(bc + l * 32);
                    float4 Ba = bv[2 * sh], Bb = bv[2 * sh + 1];
                    float4 Ca = bv[4 + 2 * sh], Cb = bv[5 + 2 * sh];
                    float y0 = 0.f;
                    #pragma unroll
                    for (int i = 0; i < 8; i++) {
                        float Bi = (i < 4) ? ((i == 0) ? Ba.x : (i == 1) ? Ba.y : (i == 2) ? Ba.z : Ba.w)
                                           : ((i == 4) ? Bb.x : (i == 5) ? Bb.y : (i == 6) ? Bb.z : Bb.w);
                        float Ci = (i < 4) ? ((i == 0) ? Ca.x : (i == 1) ? Ca.y : (i == 2) ? Ca.z : Ca.w)
                                           : ((i == 4) ? Cb.x : (i == 5) ? Cb.y : (i == 6) ? Cb.z : Cb.w);
                        float aa = -__expf(A_log_i[d * 16 + sh * 8 + i]) * LOG2E;
                        float dA = EXP2F(dtc * aa);
                        hs[i] = fmaf(dA, hs[i], dtu * Bi);
                        y0 = fmaf(hs[i], Ci, y0);
                    }
                    float y = y0 + __shfl_xor(y0, 1);
                    float v = fmaf(u_ld, Dpd, y) * z_ld;
                    if (sh == 0) ucio[l * 52 + d] = v;
                }
            }
        }
        __syncthreads();

        // 6. out matmul + residual -> s_out (z overlay; z dead after scan).
        if (tid < 192) {
            int e = tid >> 3, lg = tid & 7;
            const float4* w4 = (const float4*)(out_w_i + e * 48);
            float4 w[12];
            #pragma unroll
            for (int q = 0; q < 12; q++) w[q] = w4[q];
            for (int l = lg; l < NP_; l += 8) {
                const float4* f4 = (const float4*)(s_ucf + l * 52);
                const float4* b4 = (const float4*)(s_ucb + l * 52);
                float acc = s_h[l * 24 + e];   // residual
                #pragma unroll
                for (int q = 0; q < 12; q++) {
                    float4 af = f4[q], ab = b4[q];
                    float ax = af.x + ab.x, ay = af.y + ab.y, az = af.z + ab.z, aw = af.w + ab.w;
                    acc = fmaf(ax, w[q].x, fmaf(ay, w[q].y, fmaf(az, w[q].z, fmaf(aw, w[q].w, acc))));
                }
                s_out[l * 24 + e] = acc;
            }
        }
        __syncthreads();

        // 7. LN2: s_out -> s_h
        ln_rows(s_out, s_h, P.ln2_g + il * 24, P.ln2_b + il * 24, tid);
        __syncthreads();
    }

    // ---------------- gated attention pooling ----------------
    for (int idx = tid; idx < NP_ * 24; idx += 256) {
        int l = idx / 24, d2 = idx - l * 24;
        const float* w = P.attn_w + d2 * 24;
        const float* hr = s_h + l * 24;
        float acc = P.attn_b[d2];
        #pragma unroll
        for (int e = 0; e < 24; e++) acc = fmaf(hr[e], w[e], acc);
        s_u[idx] = tanhf(acc) * P.ctx[d2];
    }
    __syncthreads();
    if (tid < NP_) {
        float s = 0.f;
        for (int d = 0; d < 24; d++) s += s_u[tid * 24 + d];
        s_dtrf[tid] = s;
    }
    __syncthreads();
    if (tid < 64) {
        float v = (tid < NP_) ? s_dtrf[tid] : -1e30f;
        float m = v;
        #pragma unroll
        for (int o = 32; o >= 1; o >>= 1) m = fmaxf(m, __shfl_xor(m, o));
        float e = (tid < NP_) ? __expf(v - m) : 0.f;
        float s = e;
        #pragma unroll
        for (int o = 32; o >= 1; o >>= 1) s += __shfl_xor(s, o);
        if (tid < NP_) s_dtrf[tid] = __fdividef(e, s);
    }
    __syncthreads();
    if (tid < 24) {
        float acc = 0.f;
        for (int l = 0; l < NP_; l++) acc = fmaf(s_dtrf[l], s_h[l * 24 + tid], acc);
        P.cout[n * 24 + tid] = acc;
    }
}

// ---------------- kernel 2: channel mean + head LN + linear ----------------
__global__ __launch_bounds__(64) void head_kernel(const float* __restrict__ cws,
                                                  const float* __restrict__ hg,
                                                  const float* __restrict__ hb,
                                                  const float* __restrict__ hw,
                                                  const float* __restrict__ hbias,
                                                  float* __restrict__ out) {
    __shared__ float sy[24];
    int bidx = blockIdx.x, t = threadIdx.x;
    float c = 0.f;
    if (t < 24) {
        float acc = 0.f;
        for (int j = 0; j < C_; j++) acc += cws[(bidx * C_ + j) * 24 + t];
        c = acc * (1.f / 9.f);
    }
    float s = (t < 24) ? c : 0.f;
    #pragma unroll
    for (int o = 32; o >= 1; o >>= 1) s += __shfl_xor(s, o);
    float mu = s * (1.f / 24.f);
    float dv = (t < 24) ? (c - mu) : 0.f;
    float q = dv * dv;
    #pragma unroll
    for (int o = 32; o >= 1; o >>= 1) q += __shfl_xor(q, o);
    float rs = rsqrtf(q * (1.f / 24.f) + 1e-5f);
    if (t < 24) sy[t] = dv * rs * hg[t] + hb[t];
    __syncthreads();
    if (t < NCLS_) {
        float acc = hbias[t];
        #pragma unroll
        for (int d = 0; d < 24; d++) acc = fmaf(sy[d], hw[t * 24 + d], acc);
        out[bidx * NCLS_ + t] = acc;
    }
}

extern "C" void kernel_launch(void* const* d_in, const int* in_sizes, int n_in,
                              void* d_out, int out_size, void* d_ws, size_t ws_size,
                              hipStream_t stream) {
    (void)in_sizes; (void)n_in; (void)out_size; (void)ws_size;
    Params P;
    P.x          = (const float*)d_in[0];
    P.stem_w     = (const float*)d_in[1];
    P.stem_bn_g  = (const float*)d_in[2];
    P.stem_bn_b  = (const float*)d_in[3];
    P.stem_bn_m  = (const float*)d_in[4];
    P.stem_bn_v  = (const float*)d_in[5];
    P.pd_w       = (const float*)d_in[6];
    P.pp_w       = (const float*)d_in[7];
    P.patch_bn_g = (const float*)d_in[8];
    P.patch_bn_b = (const float*)d_in[9];
    P.patch_bn_m = (const float*)d_in[10];
    P.patch_bn_v = (const float*)d_in[11];
    P.pos_embed  = (const float*)d_in[12];
    P.ln1_g      = (const float*)d_in[13];
    P.ln1_b      = (const float*)d_in[14];
    P.ln2_g      = (const float*)d_in[15];
    P.ln2_b      = (const float*)d_in[16];
    P.in_w       = (const float*)d_in[17];
    P.conv_w     = (const float*)d_in[18];
    P.conv_b     = (const float*)d_in[19];
    P.xproj_w    = (const float*)d_in[20];
    P.dt_w       = (const float*)d_in[21];
    P.dt_b       = (const float*)d_in[22];
    P.A_log      = (const float*)d_in[23];
    P.Dp         = (const float*)d_in[24];
    P.out_w      = (const float*)d_in[25];
    P.attn_w     = (const float*)d_in[26];
    P.attn_b     = (const float*)d_in[27];
    P.ctx        = (const float*)d_in[28];
    P.cout       = (float*)d_ws;

    mamba_seq_kernel<<<dim3(NSEQ), dim3(256), 0, stream>>>(P);
    head_kernel<<<dim3(B_), dim3(64), 0, stream>>>(
        (const float*)d_ws,
        (const float*)d_in[29],   // head_g
        (const float*)d_in[30],   // head_b
        (const float*)d_in[31],   // head_w
        (const float*)d_in[32],   // head_bias
        (float*)d_out);
}

// Round 9
// 400.217 us; speedup vs baseline: 1.0461x; 1.0461x over previous
//
#include <hip/hip_runtime.h>
#include <hip/hip_bf16.h>
#include <math.h>

// Problem constants
#define B_    256
#define C_    9
#define T_    128
#define D_    24
#define S_    16
#define NL_   4
#define DI_   48
#define NP_   29
#define NSEQ  (B_ * C_)   // 2304
#define NCLS_ 6

#define LOG2E 1.44269504088896f

#if __has_builtin(__builtin_amdgcn_exp2f)
#define EXP2F __builtin_amdgcn_exp2f
#else
#define EXP2F exp2f
#endif

__device__ __forceinline__ float fsilu(float x) {
    return __fdividef(x, 1.f + __expf(-x));
}

struct Params {
    const float *x;
    const float *stem_w, *stem_bn_g, *stem_bn_b, *stem_bn_m, *stem_bn_v;
    const float *pd_w, *pp_w, *patch_bn_g, *patch_bn_b, *patch_bn_m, *patch_bn_v;
    const float *pos_embed, *ln1_g, *ln1_b, *ln2_g, *ln2_b;
    const float *in_w, *conv_w, *conv_b, *xproj_w, *dt_w, *dt_b, *A_log, *Dp, *out_w;
    const float *attn_w, *attn_b, *ctx;
    float *cout;   // [NSEQ][24] workspace
};

// LayerNorm over 24 elems for 29 rows (stride 24), 8 threads per row.
__device__ __forceinline__ void ln_rows(const float* src, float* dst,
                                        const float* g, const float* bb, int tid) {
    int row = tid >> 3, sub = tid & 7;
    if (row < NP_) {
        const float* r = src + row * 24;
        float s = 0.f;
        for (int j = sub; j < 24; j += 8) s += r[j];
        s += __shfl_xor(s, 1); s += __shfl_xor(s, 2); s += __shfl_xor(s, 4);
        float mu = s * (1.f / 24.f);
        float v = 0.f;
        for (int j = sub; j < 24; j += 8) { float d0 = r[j] - mu; v = fmaf(d0, d0, v); }
        v += __shfl_xor(v, 1); v += __shfl_xor(v, 2); v += __shfl_xor(v, 4);
        float rs = rsqrtf(v * (1.f / 24.f) + 1e-5f);
        for (int j = sub; j < 24; j += 8) dst[row * 24 + j] = (r[j] - mu) * rs * g[j] + bb[j];
    }
}

// LDS layout (floats). 7192 floats = 28768 B -> 5 blocks/CU by LDS.
// OCCUPANCY MODEL (r6 vs r8 measured): per-SIMD wave64 VGPR file ~256 regs.
//   VGPR 64 -> 4 waves/SIMD -> 4 blocks/CU (occ 37.9%, r8)
//   VGPR 48 -> 5 waves/SIMD -> 5 blocks/CU (occ 46.9%, r6 — faster even WITH spills)
// So: __launch_bounds__(256,5) (budget ~51) AND keep every phase's live set
// under ~48 regs: scan loads B then C (never co-live), P4/P6 read weights
// from global per row (L1-resident: xproj 6.5KB, out_w 4.6KB) instead of
// w[12]=48-reg caches (r6's spill source).
// Live-range overlays (all producer/consumer pairs barrier-separated):
//   hn [696..1392)  dead after P2  -> hosts bcf
//   u  [1392..2784) dead after P3  -> hosts rest of bcf, bcb, dtrf/b
//   z  [2784..4176) dead after scan-> hosts P6 output (29x24)
//   stage-A overlay xp[132]+h0p[3264] at z..ucb region [2784..6180)
#define OF_H    0       // 29x24 residual/h
#define OF_HN   696     // 29x24 LN1 out; dead after P2
#define OF_U    1392    // 29x48 xz-u; dead after P3
#define OF_BCF  696     // 29x32 (B[16]|C[16]) fwd — overlays hn+u head
#define OF_BCB  1624    // 29x32 bwd
#define OF_DTRF 2552    // 29x2
#define OF_DTRB 2610    // 29x2  (ends 2668 < 2784)
#define OF_Z    2784    // 29x48 silu(z); dead after scan
#define OF_OUT  2784    // 29x24 P6 output (overlays z)
#define OF_UCF  4176    // 29x52 uc fwd (pad 52 kills P6 stride-48 conflicts)
#define OF_UCB  5684    // 29x52 uc bwd
#define SM_TOT  7192

__global__ __launch_bounds__(256, 5) void mamba_seq_kernel(Params P) {
    __shared__ float sm[SM_TOT];
    const int tid = threadIdx.x;
    const int n = blockIdx.x;
    const int b = n / C_, cch = n - b * C_;

    float* s_h    = sm + OF_H;
    float* s_hn   = sm + OF_HN;
    float* s_u    = sm + OF_U;
    float* s_z    = sm + OF_Z;
    float* s_out  = sm + OF_OUT;
    float* s_ucf  = sm + OF_UCF;
    float* s_ucb  = sm + OF_UCB;
    float* s_bcf  = sm + OF_BCF;
    float* s_bcb  = sm + OF_BCB;
    float* s_dtrf = sm + OF_DTRF;
    float* s_dtrb = sm + OF_DTRB;

    float* xp  = sm + OF_Z;         // [132] stage-A overlay (z..ucb region)
    float* h0p = sm + OF_Z + 132;   // [24][136]

    // ---------------- Stage A: load + stem conv(k=5,p=2) + BN + SiLU ----------------
    if (tid < 132) {
        float v = 0.f;
        int t = tid - 2;
        if (t >= 0 && t < T_) v = P.x[(b * T_ + t) * C_ + cch];
        xp[tid] = v;
    }
    for (int idx = tid; idx < 24 * 8; idx += 256) {   // zero h0p pads
        int d = idx >> 3, j = idx & 7;
        h0p[d * 136 + (j < 4 ? j : j + 128)] = 0.f;
    }
    __syncthreads();
    for (int idx = tid; idx < 24 * 128; idx += 256) {
        int d = idx >> 7, t = idx & 127;
        const float* w = P.stem_w + d * 5;
        float acc = 0.f;
        #pragma unroll
        for (int k = 0; k < 5; k++) acc = fmaf(w[k], xp[t + k], acc);
        float sc = rsqrtf(P.stem_bn_v[d] + 1e-5f) * P.stem_bn_g[d];
        float val = (acc - P.stem_bn_m[d]) * sc + P.stem_bn_b[d];
        h0p[d * 136 + 4 + t] = fsilu(val);
    }
    __syncthreads();
    // ---------------- Stage B: patch depthwise (k=16,s=4,p=4) -> pd in s_u ----------
    for (int idx = tid; idx < 24 * 31; idx += 256) {
        int d = idx / 31, l = idx - d * 31;
        const float* w = P.pd_w + d * 16;
        const float* src = h0p + d * 136 + l * 4;
        float acc = 0.f;
        #pragma unroll
        for (int k = 0; k < 16; k++) acc = fmaf(w[k], src[k], acc);
        s_u[idx] = acc;   // pd[d*31 + l]
    }
    __syncthreads();
    // pointwise DxD + BN + pos_embed -> s_h [29][24]
    for (int idx = tid; idx < NP_ * 24; idx += 256) {
        int l = idx / 24, e = idx - l * 24;
        const float* w = P.pp_w + e * 24;
        float acc = 0.f;
        #pragma unroll
        for (int d = 0; d < 24; d++) acc = fmaf(w[d], s_u[d * 31 + l], acc);
        float sc = rsqrtf(P.patch_bn_v[e] + 1e-5f) * P.patch_bn_g[e];
        acc = (acc - P.patch_bn_m[e]) * sc + P.patch_bn_b[e];
        s_h[idx] = acc + P.pos_embed[idx];
    }
    __syncthreads();

    // ---------------- Stage C: NL bidirectional mamba layers ----------------
    for (int il = 0; il < NL_; ++il) {
        const float* in_w_i   = P.in_w   + il * 96 * 24;
        const float* conv_w_i = P.conv_w + il * 48 * 4;
        const float* conv_b_i = P.conv_b + il * 48;
        const float* xpr_i    = P.xproj_w+ il * 34 * 48;
        const float* dt_w_i   = P.dt_w   + il * 48 * 2;
        const float* dt_b_i   = P.dt_b   + il * 48;
        const float* A_log_i  = P.A_log  + il * 48 * 16;
        const float* Dp_i     = P.Dp     + il * 48;
        const float* out_w_i  = P.out_w  + il * 24 * 48;

        // 1. LN1: s_h -> s_hn
        ln_rows(s_h, s_hn, P.ln1_g + il * 24, P.ln1_b + il * 24, tid);
        __syncthreads();

        // 2. xz = hn @ in_w^T. thread owns output channel j (w[6]=24 regs),
        //    iterates rows; activation row reads are LDS broadcasts.
        if (tid < 192) {
            int j  = tid >> 1;
            int l0 = (tid & 1) ? 15 : 0;
            int l1 = (tid & 1) ? NP_ : 15;
            const float4* w4 = (const float4*)(in_w_i + j * 24);
            float4 w0 = w4[0], w1 = w4[1], w2 = w4[2], w3 = w4[3], w4v = w4[4], w5 = w4[5];
            float* dst = (j < 48) ? (s_u + j) : (s_z + (j - 48));
            for (int l = l0; l < l1; ++l) {
                const float4* h4 = (const float4*)(s_hn + l * 24);
                float4 a0 = h4[0], a1 = h4[1], a2 = h4[2], a3 = h4[3], a4 = h4[4], a5 = h4[5];
                float acc;
                acc = a0.x * w0.x; acc = fmaf(a0.y, w0.y, acc); acc = fmaf(a0.z, w0.z, acc); acc = fmaf(a0.w, w0.w, acc);
                acc = fmaf(a1.x, w1.x, acc); acc = fmaf(a1.y, w1.y, acc); acc = fmaf(a1.z, w1.z, acc); acc = fmaf(a1.w, w1.w, acc);
                acc = fmaf(a2.x, w2.x, acc); acc = fmaf(a2.y, w2.y, acc); acc = fmaf(a2.z, w2.z, acc); acc = fmaf(a2.w, w2.w, acc);
                acc = fmaf(a3.x, w3.x, acc); acc = fmaf(a3.y, w3.y, acc); acc = fmaf(a3.z, w3.z, acc); acc = fmaf(a3.w, w3.w, acc);
                acc = fmaf(a4.x, w4v.x, acc); acc = fmaf(a4.y, w4v.y, acc); acc = fmaf(a4.z, w4v.z, acc); acc = fmaf(a4.w, w4v.w, acc);
                acc = fmaf(a5.x, w5.x, acc); acc = fmaf(a5.y, w5.y, acc); acc = fmaf(a5.z, w5.z, acc); acc = fmaf(a5.w, w5.w, acc);
                dst[l * 48] = acc;
            }
        }
        __syncthreads();

        // 3. causal (fwd) + anti-causal (bwd) depthwise conv k=4 + SiLU; silu(z) in place
        for (int idx = tid; idx < NP_ * 48; idx += 256) {
            int l = idx / 48, d = idx - l * 48;
            const float* w = conv_w_i + d * 4;
            float w0 = w[0], w1 = w[1], w2 = w[2], w3 = w[3];
            float bb = conv_b_i[d];
            float accf = bb, accb = bb;
            if (l >= 3) accf = fmaf(w0, s_u[(l - 3) * 48 + d], accf);
            if (l >= 2) accf = fmaf(w1, s_u[(l - 2) * 48 + d], accf);
            if (l >= 1) accf = fmaf(w2, s_u[(l - 1) * 48 + d], accf);
            accf = fmaf(w3, s_u[l * 48 + d], accf);
            if (l + 3 < NP_) accb = fmaf(w0, s_u[(l + 3) * 48 + d], accb);
            if (l + 2 < NP_) accb = fmaf(w1, s_u[(l + 2) * 48 + d], accb);
            if (l + 1 < NP_) accb = fmaf(w2, s_u[(l + 1) * 48 + d], accb);
            accb = fmaf(w3, s_u[l * 48 + d], accb);
            s_ucf[l * 52 + d] = fsilu(accf);
            s_ucb[l * 52 + d] = fsilu(accb);
            s_z[idx] = fsilu(s_z[idx]);
        }
        __syncthreads();

        // 4. dbl = uc @ xproj^T (both dirs). Weights read per-row from global
        //    (L1-resident 6.5KB) — no w[12] register cache (spill source at
        //    the 51-reg budget).
        if (tid < 204) {
            int lg = tid / 68;            // 0..2 row-group
            int ch = tid - lg * 68;       // 0..67
            int l0 = lg * 10;
            int l1 = (lg == 2) ? NP_ : (l0 + 10);
            int dir = ch >= 34;
            int j = ch - (dir ? 34 : 0);
            const float* ucp = dir ? s_ucb : s_ucf;
            const float4* w4 = (const float4*)(xpr_i + j * 48);
            float* dst; int stride;
            if (j < 2) { dst = (dir ? s_dtrb : s_dtrf) + j; stride = 2; }
            else       { dst = (dir ? s_bcb  : s_bcf ) + (j - 2); stride = 32; }
            for (int l = l0; l < l1; ++l) {
                const float4* u4 = (const float4*)(ucp + l * 52);
                float acc = 0.f;
                #pragma unroll
                for (int q = 0; q < 12; q++) {
                    float4 a = u4[q], w = w4[q];
                    acc = fmaf(a.x, w.x, fmaf(a.y, w.y, fmaf(a.z, w.z, fmaf(a.w, w.w, acc))));
                }
                dst[l * stride] = acc;
            }
        }
        __syncthreads();

        // 5. selective scans, lane-pair split: 192 lanes = 2 dirs x 48 ch x 2 halves.
        //    Register-trimmed: B loaded+consumed, then C (never co-live);
        //    dt/softplus/exp2 chain for step p+1 prefetched during step p.
        if (tid < 192) {
            const int dir = tid >= 96;
            const int rr  = tid - (dir ? 96 : 0);
            const int d   = rr >> 1;
            const int sh  = rr & 1;
            const float* dtr = dir ? s_dtrb : s_dtrf;
            float* ucio      = dir ? s_ucb  : s_ucf;   // read u; write y in place
            const float* bc  = dir ? s_bcb  : s_bcf;
            const float dtw0 = dt_w_i[d * 2], dtw1 = dt_w_i[d * 2 + 1], dtb = dt_b_i[d];
            const float Dpd = Dp_i[d];
            // structure check (rolling, no array): A[s] == (s+1)*A[0]?
            float a0 = -__expf(A_log_i[d * 16]) * LOG2E;
            bool alin = true;
            #pragma unroll
            for (int s = 1; s < 16; s++) {
                float as = -__expf(A_log_i[d * 16 + s]) * LOG2E;
                alin = alin && (fabsf(as - (s + 1) * a0) <= 1e-4f * (s + 1) * fabsf(a0));
            }
            float hs[8];
            #pragma unroll
            for (int s = 0; s < 8; s++) hs[s] = 0.f;

            if (alin) {
                // ---- prologue: prefetch dt-chain for step 0 ----
                int l = dir ? (NP_ - 1) : 0;
                float2 tt = *(const float2*)(dtr + l * 2);
                float u_ld = ucio[l * 52 + d];
                float z_ld = s_z[l * 48 + d];
                float draw = fmaf(tt.y, dtw1, fmaf(tt.x, dtw0, dtb));
                float dtc = (draw > 15.f) ? draw : __logf(1.f + __expf(draw));
                float dtu = dtc * u_ld;
                float r1 = EXP2F(dtc * a0);

                for (int p = 0; p < NP_; p++) {
                    const int lcur = l;
                    const float u_c = u_ld, z_c = z_ld, dtu_c = dtu, rc = r1;
                    // ---- prefetch dt-chain for step p+1 ----
                    if (p + 1 < NP_) {
                        l = dir ? (NP_ - 2 - p) : (p + 1);
                        tt = *(const float2*)(dtr + l * 2);
                        u_ld = ucio[l * 52 + d];
                        z_ld = s_z[l * 48 + d];
                        draw = fmaf(tt.y, dtw1, fmaf(tt.x, dtw0, dtb));
                        dtc = (draw > 15.f) ? draw : __logf(1.f + __expf(draw));
                        dtu = dtc * u_ld;
                        r1 = EXP2F(dtc * a0);
                    }
                    // powers of rc: lane covers r^(8sh+1)..r^(8sh+8), depth<=2
                    float c2 = rc * rc, c4 = c2 * c2, c8 = c4 * c4;
                    float p3 = c2 * rc, p5 = c4 * rc, p6 = c4 * c2, p7 = c4 * p3;
                    float qm = sh ? c8 : 1.0f;
                    const float4* bv = (const float4*)(bc + lcur * 32);
                    {   // B phase: load 2xfloat4, consume into hs; B dies here
                        float4 Ba = bv[2 * sh], Bb = bv[2 * sh + 1];
                        hs[0] = fmaf(rc * qm, hs[0], dtu_c * Ba.x);
                        hs[1] = fmaf(c2 * qm, hs[1], dtu_c * Ba.y);
                        hs[2] = fmaf(p3 * qm, hs[2], dtu_c * Ba.z);
                        hs[3] = fmaf(c4 * qm, hs[3], dtu_c * Ba.w);
                        hs[4] = fmaf(p5 * qm, hs[4], dtu_c * Bb.x);
                        hs[5] = fmaf(p6 * qm, hs[5], dtu_c * Bb.y);
                        hs[6] = fmaf(p7 * qm, hs[6], dtu_c * Bb.z);
                        hs[7] = fmaf(c8 * qm, hs[7], dtu_c * Bb.w);
                    }
                    float y0, y1;
                    {   // C phase
                        float4 Ca = bv[4 + 2 * sh], Cb = bv[5 + 2 * sh];
                        y0 = hs[0] * Ca.x;          y1 = hs[1] * Ca.y;
                        y0 = fmaf(hs[2], Ca.z, y0); y1 = fmaf(hs[3], Ca.w, y1);
                        y0 = fmaf(hs[4], Cb.x, y0); y1 = fmaf(hs[5], Cb.y, y1);
                        y0 = fmaf(hs[6], Cb.z, y0); y1 = fmaf(hs[7], Cb.w, y1);
                    }
                    float y = y0 + y1;
                    y += __shfl_xor(y, 1);   // combine the two state-halves
                    float v = fmaf(u_c, Dpd, y) * z_c;
                    if (sh == 0) ucio[lcur * 52 + d] = v;
                }
            } else {
                // generic fallback (A without arange structure); register-light.
                for (int p = 0; p < NP_; p++) {
                    int l = dir ? (NP_ - 1 - p) : p;
                    float2 tt = *(const float2*)(dtr + l * 2);
                    float draw = fmaf(tt.y, dtw1, fmaf(tt.x, dtw0, dtb));
                    float dtc = (draw > 15.f) ? draw : __logf(1.f + __expf(draw));
                    float u_ld = ucio[l * 52 + d];
                    float z_ld = s_z[l * 48 + d];
                    float dtu = dtc * u_ld;
                    const float4* bv = (const float4*)(bc + l * 32);
                    float4 Ba = bv[2 * sh], Bb = bv[2 * sh + 1];
                    float4 Ca = bv[4 + 2 * sh], Cb = bv[5 + 2 * sh];
                    float y0 = 0.f;
                    #pragma unroll
                    for (int i = 0; i < 8; i++) {
                        float Bi = (i < 4) ? ((i == 0) ? Ba.x : (i == 1) ? Ba.y : (i == 2) ? Ba.z : Ba.w)
                                           : ((i == 4) ? Bb.x : (i == 5) ? Bb.y : (i == 6) ? Bb.z : Bb.w);
                        float Ci = (i < 4) ? ((i == 0) ? Ca.x : (i == 1) ? Ca.y : (i == 2) ? Ca.z : Ca.w)
                                           : ((i == 4) ? Cb.x : (i == 5) ? Cb.y : (i == 6) ? Cb.z : Cb.w);
                        float aa = -__expf(A_log_i[d * 16 + sh * 8 + i]) * LOG2E;
                        float dA = EXP2F(dtc * aa);
                        hs[i] = fmaf(dA, hs[i], dtu * Bi);
                        y0 = fmaf(hs[i], Ci, y0);
                    }
                    float y = y0 + __shfl_xor(y0, 1);
                    float v = fmaf(u_ld, Dpd, y) * z_ld;
                    if (sh == 0) ucio[l * 52 + d] = v;
                }
            }
        }
        __syncthreads();

        // 6. out matmul + residual -> s_out. Weights per-row from global
        //    (L1-resident 4.6KB) — no w[12] register cache.
        if (tid < 192) {
            int e = tid >> 3, lg = tid & 7;
            const float4* w4 = (const float4*)(out_w_i + e * 48);
            for (int l = lg; l < NP_; l += 8) {
                const float4* f4 = (const float4*)(s_ucf + l * 52);
                const float4* b4 = (const float4*)(s_ucb + l * 52);
                float acc = s_h[l * 24 + e];   // residual
                #pragma unroll
                for (int q = 0; q < 12; q++) {
                    float4 af = f4[q], ab = b4[q], w = w4[q];
                    float ax = af.x + ab.x, ay = af.y + ab.y, az = af.z + ab.z, aw = af.w + ab.w;
                    acc = fmaf(ax, w.x, fmaf(ay, w.y, fmaf(az, w.z, fmaf(aw, w.w, acc))));
                }
                s_out[l * 24 + e] = acc;
            }
        }
        __syncthreads();

        // 7. LN2: s_out -> s_h
        ln_rows(s_out, s_h, P.ln2_g + il * 24, P.ln2_b + il * 24, tid);
        __syncthreads();
    }

    // ---------------- gated attention pooling ----------------
    for (int idx = tid; idx < NP_ * 24; idx += 256) {
        int l = idx / 24, d2 = idx - l * 24;
        const float* w = P.attn_w + d2 * 24;
        const float* hr = s_h + l * 24;
        float acc = P.attn_b[d2];
        #pragma unroll
        for (int e = 0; e < 24; e++) acc = fmaf(hr[e], w[e], acc);
        s_u[idx] = tanhf(acc) * P.ctx[d2];
    }
    __syncthreads();
    if (tid < NP_) {
        float s = 0.f;
        for (int d = 0; d < 24; d++) s += s_u[tid * 24 + d];
        s_dtrf[tid] = s;
    }
    __syncthreads();
    if (tid < 64) {
        float v = (tid < NP_) ? s_dtrf[tid] : -1e30f;
        float m = v;
        #pragma unroll
        for (int o = 32; o >= 1; o >>= 1) m = fmaxf(m, __shfl_xor(m, o));
        float e = (tid < NP_) ? __expf(v - m) : 0.f;
        float s = e;
        #pragma unroll
        for (int o = 32; o >= 1; o >>= 1) s += __shfl_xor(s, o);
        if (tid < NP_) s_dtrf[tid] = __fdividef(e, s);
    }
    __syncthreads();
    if (tid < 24) {
        float acc = 0.f;
        for (int l = 0; l < NP_; l++) acc = fmaf(s_dtrf[l], s_h[l * 24 + tid], acc);
        P.cout[n * 24 + tid] = acc;
    }
}

// ---------------- kernel 2: channel mean + head LN + linear ----------------
__global__ __launch_bounds__(64) void head_kernel(const float* __restrict__ cws,
                                                  const float* __restrict__ hg,
                                                  const float* __restrict__ hb,
                                                  const float* __restrict__ hw,
                                                  const float* __restrict__ hbias,
                                                  float* __restrict__ out) {
    __shared__ float sy[24];
    int bidx = blockIdx.x, t = threadIdx.x;
    float c = 0.f;
    if (t < 24) {
        float acc = 0.f;
        for (int j = 0; j < C_; j++) acc += cws[(bidx * C_ + j) * 24 + t];
        c = acc * (1.f / 9.f);
    }
    float s = (t < 24) ? c : 0.f;
    #pragma unroll
    for (int o = 32; o >= 1; o >>= 1) s += __shfl_xor(s, o);
    float mu = s * (1.f / 24.f);
    float dv = (t < 24) ? (c - mu) : 0.f;
    float q = dv * dv;
    #pragma unroll
    for (int o = 32; o >= 1; o >>= 1) q += __shfl_xor(q, o);
    float rs = rsqrtf(q * (1.f / 24.f) + 1e-5f);
    if (t < 24) sy[t] = dv * rs * hg[t] + hb[t];
    __syncthreads();
    if (t < NCLS_) {
        float acc = hbias[t];
        #pragma unroll
        for (int d = 0; d < 24; d++) acc = fmaf(sy[d], hw[t * 24 + d], acc);
        out[bidx * NCLS_ + t] = acc;
    }
}

extern "C" void kernel_launch(void* const* d_in, const int* in_sizes, int n_in,
                              void* d_out, int out_size, void* d_ws, size_t ws_size,
                              hipStream_t stream) {
    (void)in_sizes; (void)n_in; (void)out_size; (void)ws_size;
    Params P;
    P.x          = (const float*)d_in[0];
    P.stem_w     = (const float*)d_in[1];
    P.stem_bn_g  = (const float*)d_in[2];
    P.stem_bn_b  = (const float*)d_in[3];
    P.stem_bn_m  = (const float*)d_in[4];
    P.stem_bn_v  = (const float*)d_in[5];
    P.pd_w       = (const float*)d_in[6];
    P.pp_w       = (const float*)d_in[7];
    P.patch_bn_g = (const float*)d_in[8];
    P.patch_bn_b = (const float*)d_in[9];
    P.patch_bn_m = (const float*)d_in[10];
    P.patch_bn_v = (const float*)d_in[11];
    P.pos_embed  = (const float*)d_in[12];
    P.ln1_g      = (const float*)d_in[13];
    P.ln1_b      = (const float*)d_in[14];
    P.ln2_g      = (const float*)d_in[15];
    P.ln2_b      = (const float*)d_in[16];
    P.in_w       = (const float*)d_in[17];
    P.conv_w     = (const float*)d_in[18];
    P.conv_b     = (const float*)d_in[19];
    P.xproj_w    = (const float*)d_in[20];
    P.dt_w       = (const float*)d_in[21];
    P.dt_b       = (const float*)d_in[22];
    P.A_log      = (const float*)d_in[23];
    P.Dp         = (const float*)d_in[24];
    P.out_w      = (const float*)d_in[25];
    P.attn_w     = (const float*)d_in[26];
    P.attn_b     = (const float*)d_in[27];
    P.ctx        = (const float*)d_in[28];
    P.cout       = (float*)d_ws;

    mamba_seq_kernel<<<dim3(NSEQ), dim3(256), 0, stream>>>(P);
    head_kernel<<<dim3(B_), dim3(64), 0, stream>>>(
        (const float*)d_ws,
        (const float*)d_in[29],   // head_g
        (const float*)d_in[30],   // head_b
        (const float*)d_in[31],   // head_w
        (const float*)d_in[32],   // head_bias
        (float*)d_out);
}